// Round 7
// baseline (298.664 us; speedup 1.0000x reference)
//
#include <hip/hip_runtime.h>
#include <stdint.h>

typedef unsigned short u16;
typedef __attribute__((ext_vector_type(4))) float f32x4;
typedef __attribute__((ext_vector_type(8))) __bf16 bf16x8;

#if __has_builtin(__builtin_amdgcn_exp2f)
#define EXP2(x) __builtin_amdgcn_exp2f(x)
#else
#define EXP2(x) exp2f(x)
#endif

static __device__ __forceinline__ float bf2f(u16 u) {
    union { uint32_t i; float f; } v; v.i = ((uint32_t)u) << 16; return v.f;
}
static __device__ __forceinline__ u16 f2bf(float f) {          // RNE
    union { float f; uint32_t i; } v; v.f = f;
    return (u16)((v.i + 0x7FFFu + ((v.i >> 16) & 1u)) >> 16);
}
static __device__ __forceinline__ u16 f2bf_fast(float f) {     // round-half-up (P matrix only)
    union { float f; uint32_t i; } v; v.f = f;
    return (u16)((v.i + 0x8000u) >> 16);
}

// async global->LDS DMA, 16 B per lane; lds dest = wave-uniform base + lane*16
static __device__ __forceinline__ void gl2lds16(const u16* g, u16* lds) {
    __builtin_amdgcn_global_load_lds(
        (const __attribute__((address_space(1))) void*)g,
        (__attribute__((address_space(3))) void*)lds, 16, 0, 0);
}

// ---------------------------------------------------------------- f32 -> bf16 cast (weights only)
struct CastArgs { const float* src[4]; u16* dst[4]; };

__global__ __launch_bounds__(256)
void cast_kernel(CastArgs a) {
    int bid = blockIdx.x;
    int arr = bid >> 6, boff = bid & 63;
    const float* s = a.src[arr] + (size_t)boff * 16384;
    u16* d = a.dst[arr] + (size_t)boff * 16384;
    const int tid = threadIdx.x;
#pragma unroll
    for (int i = 0; i < 8; ++i) {
        int c = tid + i * 256;
        float4 f0 = *(const float4*)(s + c * 8);
        float4 f1 = *(const float4*)(s + c * 8 + 4);
        u16 o[8];
        o[0] = f2bf(f0.x); o[1] = f2bf(f0.y); o[2] = f2bf(f0.z); o[3] = f2bf(f0.w);
        o[4] = f2bf(f1.x); o[5] = f2bf(f1.y); o[6] = f2bf(f1.z); o[7] = f2bf(f1.w);
        *(uint4*)(d + c * 8) = *(const uint4*)o;
    }
}

// ---------------------------------------------------------------- mask flags
__global__ __launch_bounds__(256)
void flags_kernel(const int* __restrict__ mask, int* __restrict__ flags) {
    const int qb = blockIdx.x, kt = blockIdx.y;
    const int tid = threadIdx.x;
    int ok = 1;
#pragma unroll
    for (int i = 0; i < 8; ++i) {
        int c = tid + i * 256;
        int row = c >> 4, cg = c & 15;
        int4 m4 = *(const int4*)&mask[(size_t)(qb * 128 + row) * 2048 + kt * 64 + cg * 4];
        ok &= (m4.x != 0) & (m4.y != 0) & (m4.z != 0) & (m4.w != 0);
    }
    int wall = __all(ok) ? 1 : 0;
    __shared__ int red[4];
    if ((tid & 63) == 0) red[tid >> 6] = wall;
    __syncthreads();
    if (tid == 0) flags[qb * 32 + kt] = red[0] & red[1] & red[2] & red[3];
}

// ---------------------------------------------------------------- XA = x @ A^T  + fused x->bf16 cast
struct XaArgs { const float* x[3]; const float* A[3]; float* o[3]; u16* xb[3]; };

__global__ __launch_bounds__(256)
void xa_kernel(XaArgs a) {
    const int z = blockIdx.y;
    const int row = blockIdx.x * 4 + (threadIdx.x >> 6);
    const int lane = threadIdx.x & 63;
    const float* xr = a.x[z] + (size_t)row * 1024 + lane * 16;
    float xv[16];
#pragma unroll
    for (int j = 0; j < 4; ++j) *(float4*)&xv[j * 4] = *(const float4*)(xr + j * 4);
    {
        u16 ob[16];
#pragma unroll
        for (int j = 0; j < 16; ++j) ob[j] = f2bf(xv[j]);
        u16* dp = a.xb[z] + (size_t)row * 1024 + lane * 16;
        *(uint4*)dp = *(const uint4*)&ob[0];
        *(uint4*)(dp + 8) = *(const uint4*)&ob[8];
    }
    float s[8];
#pragma unroll
    for (int r = 0; r < 8; ++r) {
        const float* ar = a.A[z] + (size_t)r * 1024 + lane * 16;
        float av[16];
#pragma unroll
        for (int j = 0; j < 4; ++j) *(float4*)&av[j * 4] = *(const float4*)(ar + j * 4);
        float acc = 0.f;
#pragma unroll
        for (int j = 0; j < 16; ++j) acc += xv[j] * av[j];
#pragma unroll
        for (int off = 1; off < 64; off <<= 1) acc += __shfl_xor(acc, off, 64);
        s[r] = acc;
    }
    if (lane == 0) {
#pragma unroll
        for (int r = 0; r < 8; ++r) a.o[z][(size_t)row * 8 + r] = s[r];
    }
}

// ---------------------------------------------------------------- GEMM  C = (X·W^T + bias + 2·XA·Bm^T) * oscale
// Double-buffered BK=32 DMA K-loop: ONE barrier per iter, next tile's DMA in
// flight across the barrier (AITER-style). XOR chunk swizzle (4 chunks, row&3).
struct GemmPtrs { const u16* X; const u16* W; const float* bias; const float* XA; const float* Bm; void* out; int transT; float oscale; };
struct GemmArgs { GemmPtrs p[3]; };

#define LST 136  // straight epilogue staging row stride (u16)
#define LTT 72   // transposed epilogue staging row stride (u16)

template <int WMT, int WNT, int LORA>
__global__ __launch_bounds__(256, 2)
void gemm_kernel(GemmArgs args) {
    constexpr int BM = WMT * 32, BN = WNT * 32;
    constexpr int MBLK = 4096 / BM;
    constexpr int IPA = BM / 64;   // DMA insts/wave for A (16 rows x 32 cols each)
    constexpr int IPB = BN / 64;
    __shared__ alignas(16) u16 smem[2][(BM + BN) * 32];

    const GemmPtrs gp = args.p[blockIdx.z];
    const int tid = threadIdx.x;
    const int lane = tid & 63, wave = tid >> 6;
    const int wm = wave >> 1, wn = wave & 1;
    const int l15 = lane & 15, l4 = lane >> 4;
    const int id = blockIdx.x;
    const int m0 = (id % MBLK) * BM, n0 = (id / MBLK) * BN;

    // staging: 16 rows/inst; lane -> row srow4, physical chunk lane&3 holds logical (lane&3)^(srow4&3)
    const int srow4 = lane >> 2;
    const int scol4 = ((lane & 3) ^ (srow4 & 3)) * 8;

    const f32x4 fz = {0.f, 0.f, 0.f, 0.f};
    f32x4 acc[WMT][WNT];
#pragma unroll
    for (int i = 0; i < WMT; ++i)
#pragma unroll
        for (int j = 0; j < WNT; ++j) acc[i][j] = fz;

    auto stage = [&](int kb, int buf) {
#pragma unroll
        for (int i = 0; i < IPA; ++i) {
            int base = (wave * IPA + i) * 16;
            gl2lds16(gp.X + (size_t)(m0 + base + srow4) * 1024 + kb * 32 + scol4,
                     &smem[buf][base * 32]);
        }
#pragma unroll
        for (int i = 0; i < IPB; ++i) {
            int base = (wave * IPB + i) * 16;
            gl2lds16(gp.W + (size_t)(n0 + base + srow4) * 1024 + kb * 32 + scol4,
                     &smem[buf][BM * 32 + base * 32]);
        }
    };

    stage(0, 0);
    for (int kb = 0; kb < 32; ++kb) {
        asm volatile("s_waitcnt vmcnt(0)" ::: "memory");   // my tile-kb DMA landed
        __syncthreads();                                    // everyone's landed; prev reads done
        if (kb < 31) stage(kb + 1, (kb + 1) & 1);          // next tile flies during compute
        const u16* As = &smem[kb & 1][0];
        const u16* Bs = &smem[kb & 1][BM * 32];
        bf16x8 af[WMT], bfr[WNT];
#pragma unroll
        for (int mt = 0; mt < WMT; ++mt) {
            int x = wm * (WMT * 16) + mt * 16 + l15;
            af[mt] = *(const bf16x8*)&As[x * 32 + ((l4 ^ (l15 & 3)) * 8)];
        }
#pragma unroll
        for (int nt = 0; nt < WNT; ++nt) {
            int y = wn * (WNT * 16) + nt * 16 + l15;
            bfr[nt] = *(const bf16x8*)&Bs[y * 32 + ((l4 ^ (l15 & 3)) * 8)];
        }
#pragma unroll
        for (int mt = 0; mt < WMT; ++mt)
#pragma unroll
            for (int nt = 0; nt < WNT; ++nt)
                acc[mt][nt] = __builtin_amdgcn_mfma_f32_16x16x32_bf16(af[mt], bfr[nt], acc[mt][nt], 0, 0, 0);
    }

    u16* smflat = &smem[0][0];
    if constexpr (LORA) {
        // ---- fold (bias + 2*XA·Bm^T) and oscale into acc (BM==BN==128) ----
        __syncthreads();
        float* XAs = (float*)smflat;          // [128][8] f32
        float* Bms = XAs + 1024;              // [128][8] f32
        {
            int rr = tid >> 1, hf = (tid & 1) * 4;
            *(float4*)&XAs[rr * 8 + hf] = *(const float4*)&gp.XA[(size_t)(m0 + rr) * 8 + hf];
            if (tid < 128) {
                *(float4*)&Bms[tid * 8]     = *(const float4*)&gp.Bm[(size_t)(n0 + tid) * 8];
                *(float4*)&Bms[tid * 8 + 4] = *(const float4*)&gp.Bm[(size_t)(n0 + tid) * 8 + 4];
            }
        }
        __syncthreads();
        const float osc = gp.oscale;
        float bmv[WNT][8], bsv[WNT];
#pragma unroll
        for (int nt = 0; nt < WNT; ++nt) {
            int nloc = wn * 64 + nt * 16 + l15;
            bsv[nt] = gp.bias[n0 + nloc];
#pragma unroll
            for (int q8 = 0; q8 < 8; ++q8) bmv[nt][q8] = Bms[nloc * 8 + q8];
        }
#pragma unroll
        for (int mt = 0; mt < WMT; ++mt)
#pragma unroll
            for (int r = 0; r < 4; ++r) {
                int mloc = wm * 64 + mt * 16 + l4 * 4 + r;
                float xa8[8];
                *(float4*)&xa8[0] = *(const float4*)&XAs[mloc * 8];
                *(float4*)&xa8[4] = *(const float4*)&XAs[mloc * 8 + 4];
#pragma unroll
                for (int nt = 0; nt < WNT; ++nt) {
                    float lora = 0.f;
#pragma unroll
                    for (int q8 = 0; q8 < 8; ++q8) lora += xa8[q8] * bmv[nt][q8];
                    acc[mt][nt][r] = (acc[mt][nt][r] + bsv[nt] + 2.0f * lora) * osc;
                }
            }
        __syncthreads();

        u16* outp = (u16*)gp.out;
        const int bb = m0 >> 11;
        if (gp.transT) {
            // ---- transposed staging: store V plane as [h][d][t] ----
            u16* Lst = smflat;   // [128][LTT]
#pragma unroll
            for (int ch = 0; ch < 2; ++ch) {
#pragma unroll
                for (int mt2 = 0; mt2 < 2; ++mt2) {
                    int mt = ch * 2 + mt2;
#pragma unroll
                    for (int nt = 0; nt < WNT; ++nt)
#pragma unroll
                        for (int r = 0; r < 4; ++r)
                            Lst[(wn * 64 + nt * 16 + l15) * LTT + wm * 32 + mt2 * 16 + l4 * 4 + r] =
                                f2bf(acc[mt][nt][r]);
                }
                __syncthreads();
#pragma unroll
                for (int j = 0; j < 4; ++j) {
                    int w = tid + j * 256;
                    int nl = w >> 3, seg = w & 7;
                    uint4 val = *(const uint4*)&Lst[nl * LTT + seg * 8];
                    int n = n0 + nl, hh = n >> 6, dd = n & 63;
                    int c0 = seg * 8;
                    int gm = m0 + (c0 >> 5) * 64 + ch * 32 + (c0 & 31);
                    int t = gm & 2047;
                    *(uint4*)&outp[(((size_t)(bb * 16 + hh)) * 64 + dd) * 2048 + t] = val;
                }
                __syncthreads();
            }
        } else {
            // ---- straight staging: [h][t][d] layout ----
            u16* Ls = smflat;    // [64][LST]
#pragma unroll
            for (int ch = 0; ch < 2; ++ch) {
#pragma unroll
                for (int mt2 = 0; mt2 < 2; ++mt2) {
                    int mt = ch * 2 + mt2;
#pragma unroll
                    for (int nt = 0; nt < WNT; ++nt)
#pragma unroll
                        for (int r = 0; r < 4; ++r)
                            Ls[(wm * 32 + mt2 * 16 + l4 * 4 + r) * LST + wn * 64 + nt * 16 + l15] =
                                f2bf(acc[mt][nt][r]);
                }
                __syncthreads();
#pragma unroll
                for (int j = 0; j < 4; ++j) {
                    int w = tid + j * 256;
                    int lrow = w >> 4, seg = w & 15;
                    uint4 val = *(const uint4*)&Ls[lrow * LST + seg * 8];
                    int gm = m0 + (lrow >> 5) * 64 + ch * 32 + (lrow & 31);
                    int t = gm & 2047;
                    int n = n0 + seg * 8, hh = n >> 6, dd = n & 63;
                    *(uint4*)&outp[(((size_t)(bb * 16 + hh)) * 2048 + t) * 64 + dd] = val;
                }
                __syncthreads();
            }
        }
    } else {
        float* outp = (float*)gp.out;
#pragma unroll
        for (int mt = 0; mt < WMT; ++mt)
#pragma unroll
            for (int r = 0; r < 4; ++r) {
                int m = m0 + wm * (WMT * 16) + mt * 16 + l4 * 4 + r;
#pragma unroll
                for (int nt = 0; nt < WNT; ++nt) {
                    int n = n0 + wn * (WNT * 16) + nt * 16 + l15;
                    outp[(size_t)m * 1024 + n] = acc[mt][nt][r] + gp.bias[n];
                }
            }
    }
}

// ---------------------------------------------------------------- flash attention
// 64 q-rows/block, double-buffered K/V DMA, one barrier per kt. Q pre-scaled by
// 0.125*log2e in gemm1 so p = exp2(s) (softmax shift-invariant). LDS = 40 KB.
__global__ __launch_bounds__(256, 4)
void attn_kernel(const u16* __restrict__ QKV, const int* __restrict__ mask,
                 const int* __restrict__ flags, u16* __restrict__ Xo) {
    const int qb = blockIdx.x >> 5;
    const int bh = blockIdx.x & 31;
    const int b = bh >> 4, h = bh & 15;
    const int tid = threadIdx.x;
    const int lane = tid & 63, wave = tid >> 6;
    const int l15 = lane & 15, l4 = lane >> 4;

    __shared__ alignas(16) u16 Ks[2][64 * 64];
    __shared__ alignas(16) u16 Vts[2][64 * 64];   // [d][k-tile]
    __shared__ alignas(16) u16 Ps[64 * 64];       // chunk-swizzled by (row>>2)&3

    const size_t plane = (size_t)2 * 16 * 2048 * 64;
    const u16* Qg = QKV + (size_t)(b * 16 + h) * 2048 * 64;   // [t][d] (pre-scaled)
    const u16* Kg = Qg + plane;                                // [t][d]
    const u16* Vg = Kg + plane;                                // [d][t]

    const int srow = lane >> 3;
    const int scol = ((lane & 7) ^ srow) * 8;

    bf16x8 qa[2];
#pragma unroll
    for (int kk2 = 0; kk2 < 2; ++kk2)
        qa[kk2] = *(const bf16x8*)&Qg[(size_t)(qb * 64 + wave * 16 + l15) * 64 + kk2 * 32 + l4 * 8];

    const f32x4 fz = {0.f, 0.f, 0.f, 0.f};
    f32x4 accO[4];
    float lsum[4];
#pragma unroll
    for (int dt = 0; dt < 4; ++dt) accO[dt] = fz;
#pragma unroll
    for (int r = 0; r < 4; ++r) lsum[r] = 0.f;

    auto stageKV = [&](int kt, int buf) {
#pragma unroll
        for (int i = 0; i < 2; ++i) {
            int qq = wave * 2 + i;
            gl2lds16(Kg + (size_t)(kt * 64 + qq * 8 + srow) * 64 + scol, &Ks[buf][qq * 512]);
            gl2lds16(Vg + (size_t)(qq * 8 + srow) * 2048 + kt * 64 + scol, &Vts[buf][qq * 512]);
        }
    };

    stageKV(0, 0);
    for (int kt = 0; kt < 32; ++kt) {
        asm volatile("s_waitcnt vmcnt(0)" ::: "memory");
        __syncthreads();
        if (kt < 31) stageKV(kt + 1, (kt + 1) & 1);
        const u16* K_ = Ks[kt & 1];
        const u16* V_ = Vts[kt & 1];

        // S' = Qs K^T (scale folded into Q)
        f32x4 accS[4];
#pragma unroll
        for (int nt = 0; nt < 4; ++nt) accS[nt] = fz;
#pragma unroll
        for (int kk2 = 0; kk2 < 2; ++kk2) {
            bf16x8 kf[4];
#pragma unroll
            for (int nt = 0; nt < 4; ++nt)
                kf[nt] = *(const bf16x8*)&K_[(nt * 16 + l15) * 64 + (((kk2 * 4 + l4) ^ (l15 & 7)) * 8)];
#pragma unroll
            for (int nt = 0; nt < 4; ++nt)
                accS[nt] = __builtin_amdgcn_mfma_f32_16x16x32_bf16(qa[kk2], kf[nt], accS[nt], 0, 0, 0);
        }

        if (flags[(qb >> 1) * 32 + kt] == 0) {
#pragma unroll
            for (int nt = 0; nt < 4; ++nt)
#pragma unroll
                for (int r = 0; r < 4; ++r) {
                    int qrow = qb * 64 + wave * 16 + l4 * 4 + r;
                    int kcol = kt * 64 + nt * 16 + l15;
                    if (mask[(size_t)qrow * 2048 + kcol] == 0) accS[nt][r] = -1e9f;
                }
        }

        // p = exp2(s')  (shift cancels in normalization)
#pragma unroll
        for (int r = 0; r < 4; ++r) {
            float part = 0.f;
#pragma unroll
            for (int nt = 0; nt < 4; ++nt) {
                float p = EXP2(accS[nt][r]);
                accS[nt][r] = p;
                part += p;
            }
            lsum[r] += part;
        }

        // P: C-layout regs -> LDS (A-layout readable), chunk swizzle by (row>>2)&3
#pragma unroll
        for (int nt = 0; nt < 4; ++nt)
#pragma unroll
            for (int r = 0; r < 4; ++r) {
                int row = wave * 16 + l4 * 4 + r;
                int phys = (nt * 2 + (l15 >> 3)) ^ l4;
                Ps[row * 64 + phys * 8 + (l15 & 7)] = f2bf_fast(accS[nt][r]);
            }
        asm volatile("s_waitcnt lgkmcnt(0)" : : : "memory");

        // O += P V
#pragma unroll
        for (int kk2 = 0; kk2 < 2; ++kk2) {
            bf16x8 pa = *(const bf16x8*)&Ps[(wave * 16 + l15) * 64 + (((kk2 * 4 + l4) ^ (l15 >> 2)) * 8)];
            bf16x8 vf[4];
#pragma unroll
            for (int dt = 0; dt < 4; ++dt)
                vf[dt] = *(const bf16x8*)&V_[(dt * 16 + l15) * 64 + (((kk2 * 4 + l4) ^ (l15 & 7)) * 8)];
#pragma unroll
            for (int dt = 0; dt < 4; ++dt)
                accO[dt] = __builtin_amdgcn_mfma_f32_16x16x32_bf16(pa, vf[dt], accO[dt], 0, 0, 0);
        }
    }

    float inv[4];
#pragma unroll
    for (int r = 0; r < 4; ++r) {
        float s = lsum[r];
#pragma unroll
        for (int off = 1; off < 16; off <<= 1) s += __shfl_xor(s, off, 64);
        inv[r] = 1.0f / s;
    }

    // LDS-staged coalesced output (same swizzled layout)
#pragma unroll
    for (int dt = 0; dt < 4; ++dt)
#pragma unroll
        for (int r = 0; r < 4; ++r) {
            int row = wave * 16 + l4 * 4 + r;
            int phys = (dt * 2 + (l15 >> 3)) ^ l4;
            Ps[row * 64 + phys * 8 + (l15 & 7)] = f2bf(accO[dt][r] * inv[r]);
        }
    __syncthreads();
#pragma unroll
    for (int j = 0; j < 2; ++j) {
        int w = tid + j * 256;            // 512: 64 rows x 8 segs
        int row = w >> 3, seg = w & 7;
        int phys = seg ^ ((row >> 2) & 3);
        uint4 val = *(const uint4*)&Ps[row * 64 + phys * 8];
        int t = qb * 64 + row;
        *(uint4*)&Xo[((size_t)(b * 2048 + t)) * 1024 + h * 64 + seg * 8] = val;
    }
}

// ---------------------------------------------------------------- launch
extern "C" void kernel_launch(void* const* d_in, const int* in_sizes, int n_in,
                              void* d_out, int out_size, void* d_ws, size_t ws_size,
                              hipStream_t stream) {
    const float* q    = (const float*)d_in[0];
    const float* k    = (const float*)d_in[1];
    const float* v    = (const float*)d_in[2];
    const int*   mask = (const int*)d_in[3];
    const float* Wq = (const float*)d_in[4];
    const float* bq = (const float*)d_in[5];
    const float* Aq = (const float*)d_in[6];
    const float* Bq = (const float*)d_in[7];
    const float* Wk = (const float*)d_in[8];
    const float* bk = (const float*)d_in[9];
    const float* Ak = (const float*)d_in[10];
    const float* Bk = (const float*)d_in[11];
    const float* Wv = (const float*)d_in[12];
    const float* bv = (const float*)d_in[13];
    const float* Av = (const float*)d_in[14];
    const float* Bv = (const float*)d_in[15];
    const float* Wo = (const float*)d_in[16];
    const float* bo = (const float*)d_in[17];

    char* ws = (char*)d_ws;
    u16*   QKV   = (u16*)ws;                    // Q,K: [b][h][t][d]; V: [b][h][d][t]
    u16*   qb16  = (u16*)(ws + 25165824);
    u16*   kb16  = (u16*)(ws + 33554432);
    u16*   vb16  = (u16*)(ws + 41943040);
    u16*   Wqb   = (u16*)(ws + 50331648);
    u16*   Wkb   = (u16*)(ws + 52428800);
    u16*   Wvb   = (u16*)(ws + 54525952);
    u16*   Wob   = (u16*)(ws + 56623104);
    float* XAbuf = (float*)(ws + 58720256);
    int*   flags = (int*)(ws + 59113472);
    u16*   Xbuf  = qb16;

    flags_kernel<<<dim3(16, 32), dim3(256), 0, stream>>>(mask, flags);

    XaArgs xa;
    xa.x[0] = q;  xa.x[1] = k;  xa.x[2] = v;
    xa.A[0] = Aq; xa.A[1] = Ak; xa.A[2] = Av;
    xa.o[0] = XAbuf; xa.o[1] = XAbuf + 32768; xa.o[2] = XAbuf + 65536;
    xa.xb[0] = qb16; xa.xb[1] = kb16; xa.xb[2] = vb16;
    xa_kernel<<<dim3(1024, 3), dim3(256), 0, stream>>>(xa);

    CastArgs ca;
    ca.src[0] = Wq; ca.src[1] = Wk; ca.src[2] = Wv; ca.src[3] = Wo;
    ca.dst[0] = Wqb; ca.dst[1] = Wkb; ca.dst[2] = Wvb; ca.dst[3] = Wob;
    cast_kernel<<<dim3(256), dim3(256), 0, stream>>>(ca);

    const float QSCALE = 0.1803368801f;   // 0.125 * log2(e)
    GemmArgs g1;
    g1.p[0] = GemmPtrs{qb16, Wqb, bq, XAbuf,         Bq, (void*)QKV,             0, QSCALE};
    g1.p[1] = GemmPtrs{kb16, Wkb, bk, XAbuf + 32768, Bk, (void*)(QKV + 4194304), 0, 1.0f};
    g1.p[2] = GemmPtrs{vb16, Wvb, bv, XAbuf + 65536, Bv, (void*)(QKV + 8388608), 1, 1.0f};
    gemm_kernel<4, 4, 1><<<dim3(256, 1, 3), dim3(256), 0, stream>>>(g1);

    attn_kernel<<<dim3(1024), dim3(256), 0, stream>>>(QKV, mask, flags, Xbuf);

    GemmArgs g2;
    g2.p[0] = GemmPtrs{Xbuf, Wob, bo, nullptr, nullptr, d_out, 0, 1.0f};
    g2.p[1] = g2.p[0];
    g2.p[2] = g2.p[0];
    gemm_kernel<2, 4, 0><<<dim3(512, 1, 1), dim3(256), 0, stream>>>(g2);
}